// Round 12
// baseline (490.389 us; speedup 1.0000x reference)
//
#include <hip/hip_runtime.h>

// Subtractor50Bit: A - B via two's complement, N rows x 50 bits ({0,1} floats).
// out = [result (N*50 floats), borrow (N floats)].
//
// R11: R8's persistent max-occupancy shell x R9's nontemporal loads.
// Session model (11 rounds of evidence): allocating reads cycle 400MB of
// inputs through the 256MB MALL -> scattered ~50% residency -> the HBM
// read stream is a random subsample -> capped at ~2.7 TB/s regardless of
// every CU-side knob (R0-R8, R10 all confirm; R10's FETCH was bit-identical
// to plain-plain). Full NT read-bypass (R9) is the only regime that escapes
// the cap: kernel dropped below the harness's 124us fill kernels, bench
// best. Residual deficit vs the 6.6 TB/s fills = read-request concurrency:
// R9 kept the non-persistent 39%-occupancy shell (bursty, ~40% read duty).
// R8 proved the occupancy fix mechanically (82% occ) but was poisoned by
// allocating-read thrash (FETCH 298MB) -- a mechanism NT reads structurally
// eliminate. This round composes the two:
//   - 2048 persistent blocks x 256 thr = 32 waves/CU, grid-striding tiles
//   - __launch_bounds__(256, 8): VGPR<=64, all 8 waves/SIMD resident
//   - all input loads NONTEMPORAL (v2f ext_vector; no MALL allocation)
//   - plain stores (NT-store: measured -13% in R7b)
// Gates: Occ>=80, VGPR<=64. Signatures: FETCH ~390-400MB (sequential, not
// 298-scattered), WRITE ~199-210MB (>250 => shell-induced amplification =>
// revert to R9). Win: kernel ~95-115us, bench ~390-415. Null (bench>=436):
// R9 final, roofline call.

constexpr int BITS = 50;
constexpr unsigned long long MASK50 = (1ULL << BITS) - 1ULL;

// clang-native vector: required by __builtin_nontemporal_load
// (HIP float2 is a struct); layout-identical to float2 (8B, 8B-aligned).
typedef float v2f __attribute__((ext_vector_type(2)));

__device__ inline unsigned long long shfl64(unsigned long long v, int src) {
    int lo = __shfl((int)(unsigned)(v & 0xffffffffULL), src, 64);
    int hi = __shfl((int)(unsigned)(v >> 32), src, 64);
    return ((unsigned long long)(unsigned)hi << 32) | (unsigned long long)(unsigned)lo;
}

// bit i -> bit 2i (valid for i < 32)
__device__ inline unsigned long long spread2(unsigned long long x) {
    x = (x | (x << 16)) & 0x0000FFFF0000FFFFULL;
    x = (x | (x << 8))  & 0x00FF00FF00FF00FFULL;
    x = (x | (x << 4))  & 0x0F0F0F0F0F0F0F0FULL;
    x = (x | (x << 2))  & 0x3333333333333333ULL;
    x = (x | (x << 1))  & 0x5555555555555555ULL;
    return x;
}

__global__ __launch_bounds__(256, 8) void Subtractor50Bit_kernel(
    const float* __restrict__ A, const float* __restrict__ B,
    float* __restrict__ out, int N)
{
    const int lane   = threadIdx.x & 63;
    const int wv     = threadIdx.x >> 6;
    const int lane31 = lane & 31;
    const bool isLo  = lane < 32;

    const long long nTiles     = (long long)N >> 6;          // full 64-row tiles
    const long long wavesTotal = (long long)gridDim.x * 4;

    for (long long tile = (long long)blockIdx.x * 4 + wv;
         tile < nTiles; tile += wavesTotal) {

        const long long eBase = tile * 64 * BITS;            // 3200 floats/tile
        const v2f* pa = (const v2f*)(A + eBase) + lane;
        const v2f* pb = (const v2f*)(B + eBase) + lane;

        // ---- Phase 1+2 interleaved: rolling NT loads + ballots.
        // Chunk t covers elements [128t,128t+128):
        //   .x ballot = even-plane word t, .y ballot = odd-plane word t.
        // E-words parked in lanes 0..24, O-words in lanes 32..56.
        unsigned long long wa = 0, wb = 0;
        #pragma unroll
        for (int t = 0; t < 25; ++t) {
            v2f va = __builtin_nontemporal_load(pa + t * 64);
            v2f vb = __builtin_nontemporal_load(pb + t * 64);
            unsigned long long aE = __ballot(va.x != 0.0f);
            unsigned long long aO = __ballot(va.y != 0.0f);
            unsigned long long bE = __ballot(vb.x != 0.0f);
            unsigned long long bO = __ballot(vb.y != 0.0f);
            if (lane31 == t) {
                wa = isLo ? aE : aO;
                wb = isLo ? bE : bO;
            }
        }

        // ---- Phase 3: per-lane row assembly (verified R2/R3/R9).
        // Row's even bits = even-plane window [25*lane, 25*lane+25).
        const int p0 = 25 * lane;
        const int w0 = p0 >> 6;
        const int sh = p0 & 63;

        unsigned long long aE0 = shfl64(wa, w0);
        unsigned long long aE1 = shfl64(wa, w0 + 1);   // src>24 holds 0 (safe)
        unsigned long long aO0 = shfl64(wa, 32 + w0);
        unsigned long long aO1 = shfl64(wa, 33 + w0);
        unsigned long long bE0 = shfl64(wb, w0);
        unsigned long long bE1 = shfl64(wb, w0 + 1);
        unsigned long long bO0 = shfl64(wb, 32 + w0);
        unsigned long long bO1 = shfl64(wb, 33 + w0);

        unsigned long long evA = aE0 >> sh, odA = aO0 >> sh;
        unsigned long long evB = bE0 >> sh, odB = bO0 >> sh;
        if (sh > 39) {               // window straddles two plane words
            const int c = 64 - sh;   // in [1,24] -> shifts well-defined
            evA |= aE1 << c; odA |= aO1 << c;
            evB |= bE1 << c; odB |= bO1 << c;
        }
        const unsigned long long M25 = (1ULL << 25) - 1ULL;
        evA &= M25; odA &= M25; evB &= M25; odB &= M25;

        unsigned long long av = spread2(evA) | (spread2(odA) << 1);
        unsigned long long bv = spread2(evB) | (spread2(odB) << 1);

        unsigned long long diff = (av - bv) & MASK50;  // A + ~B + 1 (mod 2^50)
        float borrow = (av < bv) ? 1.0f : 0.0f;        // 1 - carry_out

        // ---- Phase 4: packed 8B stores, coalesced (verified R2/R3/R9).
        unsigned long long* po = (unsigned long long*)(out + eBase);
        #pragma unroll
        for (int j = 0; j < 25; ++j) {
            int q = j * 64 + lane;            // float2 index in [0,1600)
            int r = q / 25;                   // owning local row (magic-mul)
            int k = 2 * (q - r * 25);         // bit index within row
            unsigned long long dr = shfl64(diff, r);
            unsigned long long t2 = dr >> k;
            po[q] = ((t2 & 1ULL) ? 0x000000003F800000ULL : 0ULL)
                  | ((t2 & 2ULL) ? 0x3F80000000000000ULL : 0ULL);
        }
        // borrow segment: naturally coalesced
        out[(long long)N * BITS + tile * 64 + lane] = borrow;
    }

    // ---- remainder rows (N % 64 != 0 safety net): block 0, wave 0.
    if (blockIdx.x == 0 && wv == 0) {
        long long r = nTiles * 64 + lane;
        if (r < N) {
            unsigned long long av = 0, bv = 0;
            for (int k = 0; k < BITS; ++k) {
                av |= (unsigned long long)(A[r * BITS + k] != 0.0f) << k;
                bv |= (unsigned long long)(B[r * BITS + k] != 0.0f) << k;
            }
            unsigned long long diff = (av - bv) & MASK50;
            for (int k = 0; k < BITS; ++k)
                out[r * BITS + k] = (float)((diff >> k) & 1ULL);
            out[(long long)N * BITS + r] = (av < bv) ? 1.0f : 0.0f;
        }
    }
}

extern "C" void kernel_launch(void* const* d_in, const int* in_sizes, int n_in,
                              void* d_out, int out_size, void* d_ws, size_t ws_size,
                              hipStream_t stream) {
    const float* A = (const float*)d_in[0];
    const float* B = (const float*)d_in[1];
    float* out = (float*)d_out;
    const int N = in_sizes[0] / BITS;          // 1,000,000

    const long long nTiles = (long long)N >> 6;
    // 8 blocks/CU x 256 CUs = 2048 persistent blocks = 32 waves/CU.
    long long want = (nTiles + 3) / 4;
    if (want > 2048) want = 2048;
    if (want < 1) want = 1;
    Subtractor50Bit_kernel<<<(int)want, 256, 0, stream>>>(A, B, out, N);
}

// Round 13
// 438.769 us; speedup vs baseline: 1.1176x; 1.1176x over previous
//
#include <hip/hip_runtime.h>

// Subtractor50Bit: A - B via two's complement, N rows x 50 bits ({0,1} floats).
// out = [result (N*50 floats), borrow (N floats)].
//
// R12 = R9 verbatim (session best: bench 436.8us; all profiled dispatches
// ran below the harness's 124us / 6.6 TB/s fill kernels). Reverting per the
// R11 pre-commitment: the persistent shell amplified traffic (FETCH 296 /
// WRITE 306 MB, shell signature identical to R8) and lost despite 78% occ.
//
// Final session model (12 rounds):
// - Allocating reads cycle 400MB of input through the 256MB MALL ->
//   scattered ~50% residency -> HBM reads become a random subsample ->
//   ~2.6 TB/s cap immune to occupancy/in-flight/width/path (R0-R8, R10).
// - Full NT read-bypass (this kernel) restores a sequential HBM read
//   stream: ~604MB/rep compulsory traffic at ~4.5-4.9 TB/s effective.
// - NT stores: -13% (R7b). Asymmetric A-cached/B-NT: relaxes back to the
//   thrash equilibrium (R10, FETCH bit-identical to plain). Persistent
//   max-occupancy shell: +100MB on both streams (R8/R11).
// Remaining gap to the 6.6 TB/s pure-stream fills is the mixed 2R:1W
// stream's practical ceiling -- roofline.

constexpr int BITS = 50;
constexpr unsigned long long MASK50 = (1ULL << BITS) - 1ULL;

// clang-native vector: required by __builtin_nontemporal_load
// (HIP float2 is a struct); layout-identical to float2 (8B, 8B-aligned).
typedef float v2f __attribute__((ext_vector_type(2)));

__device__ inline unsigned long long shfl64(unsigned long long v, int src) {
    int lo = __shfl((int)(unsigned)(v & 0xffffffffULL), src, 64);
    int hi = __shfl((int)(unsigned)(v >> 32), src, 64);
    return ((unsigned long long)(unsigned)hi << 32) | (unsigned long long)(unsigned)lo;
}

// bit i -> bit 2i (valid for i < 32)
__device__ inline unsigned long long spread2(unsigned long long x) {
    x = (x | (x << 16)) & 0x0000FFFF0000FFFFULL;
    x = (x | (x << 8))  & 0x00FF00FF00FF00FFULL;
    x = (x | (x << 4))  & 0x0F0F0F0F0F0F0F0FULL;
    x = (x | (x << 2))  & 0x3333333333333333ULL;
    x = (x | (x << 1))  & 0x5555555555555555ULL;
    return x;
}

__global__ __launch_bounds__(256) void Subtractor50Bit_kernel(
    const float* __restrict__ A, const float* __restrict__ B,
    float* __restrict__ out, int N)
{
    const int lane = threadIdx.x & 63;
    const int wv   = threadIdx.x >> 6;
    const long long waveIdx = (long long)blockIdx.x * 4 + wv;
    const long long rowBase = waveIdx * 64;
    if (rowBase >= N) return;

    if (rowBase + 64 <= N) {
        // ---- full-wave fast path (64 rows, all lanes active) ----
        const long long eBase = rowBase * BITS;          // 3200 elements/wave
        const v2f* pa = (const v2f*)(A + eBase) + lane;
        const v2f* pb = (const v2f*)(B + eBase) + lane;

        // Phase 1: ALL loads issued first (independent, 512B/instr coalesced),
        // NONTEMPORAL: no MALL allocation -> sequential HBM read stream.
        v2f fa[25], fb[25];
        #pragma unroll
        for (int t = 0; t < 25; ++t) fa[t] = __builtin_nontemporal_load(pa + t * 64);
        #pragma unroll
        for (int t = 0; t < 25; ++t) fb[t] = __builtin_nontemporal_load(pb + t * 64);

        __builtin_amdgcn_sched_barrier(0);

        // Phase 2: ballots. Chunk t covers elements [128t, 128t+128):
        //   .x ballot = even-plane word t  (bit i = element 128t+2i)
        //   .y ballot = odd-plane  word t  (bit i = element 128t+2i+1)
        // E-words parked in lanes 0..24, O-words in lanes 32..56; others 0.
        unsigned long long wa = 0, wb = 0;
        const int  lane31 = lane & 31;
        const bool isLo   = lane < 32;
        #pragma unroll
        for (int t = 0; t < 25; ++t) {
            unsigned long long aE = __ballot(fa[t].x != 0.0f);
            unsigned long long aO = __ballot(fa[t].y != 0.0f);
            unsigned long long bE = __ballot(fb[t].x != 0.0f);
            unsigned long long bO = __ballot(fb[t].y != 0.0f);
            if (lane31 == t) {
                wa = isLo ? aE : aO;
                wb = isLo ? bE : bO;
            }
        }

        // Phase 3: per-lane row assembly; lane owns row (rowBase + lane).
        // Row's even bits = even-plane window [25*lane, 25*lane+25).
        const int p0 = 25 * lane;
        const int w0 = p0 >> 6;
        const int sh = p0 & 63;

        unsigned long long aE0 = shfl64(wa, w0);
        unsigned long long aE1 = shfl64(wa, w0 + 1);      // src>24 holds 0 (safe)
        unsigned long long aO0 = shfl64(wa, 32 + w0);
        unsigned long long aO1 = shfl64(wa, 33 + w0);
        unsigned long long bE0 = shfl64(wb, w0);
        unsigned long long bE1 = shfl64(wb, w0 + 1);
        unsigned long long bO0 = shfl64(wb, 32 + w0);
        unsigned long long bO1 = shfl64(wb, 33 + w0);

        unsigned long long evA = aE0 >> sh, odA = aO0 >> sh;
        unsigned long long evB = bE0 >> sh, odB = bO0 >> sh;
        if (sh > 39) {               // window straddles two plane words
            const int c = 64 - sh;   // in [1,24] here -> shifts well-defined
            evA |= aE1 << c; odA |= aO1 << c;
            evB |= bE1 << c; odB |= bO1 << c;
        }
        const unsigned long long M25 = (1ULL << 25) - 1ULL;
        evA &= M25; odA &= M25; evB &= M25; odB &= M25;

        unsigned long long av = spread2(evA) | (spread2(odA) << 1);
        unsigned long long bv = spread2(evB) | (spread2(odB) << 1);

        unsigned long long diff = (av - bv) & MASK50;     // A + ~B + 1 (mod 2^50)
        float borrow = (av < bv) ? 1.0f : 0.0f;           // 1 - carry_out

        // Phase 4: packed 8B stores, coalesced 512B/instr (plain stores;
        // NT-store was a measured regression and writes are already
        // no-allocate). float2 q covers elements [2q,2q+2), one row each.
        unsigned long long* po = (unsigned long long*)(out + eBase);
        #pragma unroll
        for (int j = 0; j < 25; ++j) {
            int q = j * 64 + lane;            // float2 index in [0,1600)
            int r = q / 25;                   // owning local row (magic-mul)
            int k = 2 * (q - r * 25);         // bit index within row
            unsigned long long dr = shfl64(diff, r);
            unsigned long long t2 = dr >> k;
            po[q] = ((t2 & 1ULL) ? 0x000000003F800000ULL : 0ULL)
                  | ((t2 & 2ULL) ? 0x3F80000000000000ULL : 0ULL);
        }
        // borrow segment: naturally coalesced
        out[(long long)N * BITS + rowBase + lane] = borrow;
    } else {
        // ---- scalar tail path (partial wave; N%64!=0 safety net) ----
        long long r = rowBase + lane;
        if (r < N) {
            unsigned long long av = 0, bv = 0;
            for (int k = 0; k < BITS; ++k) {
                av |= (unsigned long long)(A[r * BITS + k] != 0.0f) << k;
                bv |= (unsigned long long)(B[r * BITS + k] != 0.0f) << k;
            }
            unsigned long long diff = (av - bv) & MASK50;
            for (int k = 0; k < BITS; ++k)
                out[r * BITS + k] = (float)((diff >> k) & 1ULL);
            out[(long long)N * BITS + r] = (av < bv) ? 1.0f : 0.0f;
        }
    }
}

extern "C" void kernel_launch(void* const* d_in, const int* in_sizes, int n_in,
                              void* d_out, int out_size, void* d_ws, size_t ws_size,
                              hipStream_t stream) {
    const float* A = (const float*)d_in[0];
    const float* B = (const float*)d_in[1];
    float* out = (float*)d_out;
    const int N = in_sizes[0] / BITS;          // 1,000,000

    const int waves  = (N + 63) / 64;          // one wave per 64 rows
    const int blocks = (waves + 3) / 4;        // 4 waves per 256-thread block
    Subtractor50Bit_kernel<<<blocks, 256, 0, stream>>>(A, B, out, N);
}